// Round 3
// baseline (505.061 us; speedup 1.0000x reference)
//
#include <hip/hip_runtime.h>

typedef unsigned short ushort_t;
typedef __attribute__((ext_vector_type(8))) short short8;
typedef __attribute__((ext_vector_type(4))) float floatx4;

#define TWO_PI 6.28318530717958647692f

__device__ __forceinline__ float bf2f(ushort_t u) {
  union { unsigned u; float f; } v; v.u = ((unsigned)u) << 16; return v.f;
}
__device__ __forceinline__ ushort_t f2bf(float f) {
  union { float f; unsigned u; } v; v.f = f;
  unsigned r = v.u + 0x7FFFu + ((v.u >> 16) & 1u);
  return (ushort_t)(r >> 16);
}
// read input element `idx` as float, from either bf16 or fp32 buffer
__device__ __forceinline__ float ldin(const void* p, int idx, bool bf) {
  return bf ? bf2f(((const ushort_t*)p)[idx]) : ((const float*)p)[idx];
}
// per-wave runtime dtype probe on x (first 64 ushorts). bf16 N(0,1): ~64
// plausible exponents; fp32 N(0,1): ~35 (even ushorts are mantissa junk).
__device__ __forceinline__ bool detect_bf16(const void* xv) {
  const ushort_t* us = (const ushort_t*)xv;
  unsigned u = us[threadIdx.x & 63];
  int e = (u >> 7) & 0xFF;
  bool good = (e >= 110) && (e <= 133);
  unsigned long long m = __ballot(good);
  return __builtin_popcountll(m) >= 52;
}
__device__ __forceinline__ uint4 pack8f(const float* p) {
  float4 a = *(const float4*)p, b = *(const float4*)(p + 4);
  uint4 r;
  r.x = (unsigned)f2bf(a.x) | ((unsigned)f2bf(a.y) << 16);
  r.y = (unsigned)f2bf(a.z) | ((unsigned)f2bf(a.w) << 16);
  r.z = (unsigned)f2bf(b.x) | ((unsigned)f2bf(b.y) << 16);
  r.w = (unsigned)f2bf(b.z) | ((unsigned)f2bf(b.w) << 16);
  return r;
}

// ---------------------------------------------------------------------------
// Phase 1: one block (256 thr) per point -> A[p][4096] bf16 in ws.
// ---------------------------------------------------------------------------
__global__ __launch_bounds__(256) void paiconv_phase1(
    const void* __restrict__ x,      // [8,3,2048]
    const void* __restrict__ feat,   // [8,64,2048]
    const int*  __restrict__ nbr,    // [8,2048,32]
    const void* __restrict__ Brff,   // [7,32]
    const void* __restrict__ kern,   // [3,32]
    const void* __restrict__ mlpw,   // [64,64]
    const void* __restrict__ mlpb,   // [64]
    ushort_t*   __restrict__ A)      // [16384,4096] bf16
{
  const bool bf = detect_bf16(x);
  const int p = blockIdx.x;
  const int b = p >> 11;
  const int t = threadIdx.x;

  __shared__ float sRt[64][33];   // rff^T: [q][j], q<32 sin, q>=32 cos
  __shared__ float sFs[128][33];  // shuffled feats [c'][j]
  __shared__ float sP[32][33];    // perm [i][j]
  __shared__ int   sNb[32];
  __shared__ float sRel[32][3];
  __shared__ float sDis[32];
  __shared__ float sRep[3];

  const int xoff = b * 3 * 2048;

  if (t < 32) {
    int idx  = nbr[(p << 5) + t];
    int idx0 = nbr[(p << 5)];
    sNb[t] = idx;
    float rx = ldin(x, xoff + idx0, bf);
    float ry = ldin(x, xoff + 2048 + idx0, bf);
    float rz = ldin(x, xoff + 4096 + idx0, bf);
    float cx = ldin(x, xoff + idx, bf);
    float cy = ldin(x, xoff + 2048 + idx, bf);
    float cz = ldin(x, xoff + 4096 + idx, bf);
    float dx = cx - rx, dy = cy - ry, dz = cz - rz;
    sRel[t][0] = dx; sRel[t][1] = dy; sRel[t][2] = dz;
    sDis[t] = sqrtf(dx * dx + dy * dy + dz * dz);
    if (t == 0) { sRep[0] = rx; sRep[1] = ry; sRep[2] = rz; }
  }
  __syncthreads();

  // S1: RFF
  {
    int j = t >> 3, m0 = (t & 7) * 4;
    float pos[7];
    pos[0] = TWO_PI * sRep[0]; pos[1] = TWO_PI * sRep[1]; pos[2] = TWO_PI * sRep[2];
    pos[3] = TWO_PI * sRel[j][0]; pos[4] = TWO_PI * sRel[j][1]; pos[5] = TWO_PI * sRel[j][2];
    pos[6] = TWO_PI * sDis[j];
#pragma unroll
    for (int mm = 0; mm < 4; ++mm) {
      int m = m0 + mm;
      float a = 0.f;
#pragma unroll
      for (int d = 0; d < 7; ++d) a += pos[d] * ldin(Brff, d * 32 + m, bf);
      sRt[m][j]      = __sinf(a);
      sRt[m + 32][j] = __cosf(a);
    }
  }
  __syncthreads();

  // S2: mlp -> channels 64..127 (pre-shuffle), write shuffled
  {
    int c = t >> 2, jg = (t & 3) * 8;
    float acc[8];
    float bias = ldin(mlpb, c, bf);
#pragma unroll
    for (int jj = 0; jj < 8; ++jj) acc[jj] = bias;
#pragma unroll 4
    for (int q = 0; q < 64; ++q) {
      float w = ldin(mlpw, c * 64 + q, bf);
#pragma unroll
      for (int jj = 0; jj < 8; ++jj) acc[jj] += w * sRt[q][jg + jj];
    }
    int pre  = 64 + c;
    int shuf = (pre & 31) * 4 + (pre >> 5);
#pragma unroll
    for (int jj = 0; jj < 8; ++jj) sFs[shuf][jg + jj] = acc[jj];
  }

  // S3: gather features -> channels 0..63 (pre-shuffle), write shuffled
  {
    int j = t & 31, c0 = (t >> 5) * 8;
    int idx = sNb[j];
    int fbase = b * 64 * 2048 + idx;
#pragma unroll
    for (int cc = 0; cc < 8; ++cc) {
      int c = c0 + cc;
      float v = ldin(feat, fbase + c * 2048, bf);
      sFs[(c & 31) * 4 + (c >> 5)][j] = v;
    }
  }

  // S4: perm column j (threads 0..31): relu(x_rel@kern + onepad), topkmax
  if (t < 32) {
    int j = t;
    float col[32];
    float k0 = ldin(kern, j, bf), k1 = ldin(kern, 32 + j, bf), k2 = ldin(kern, 64 + j, bf);
    float s1 = 0.f;
#pragma unroll
    for (int i = 0; i < 32; ++i) {
      float v = sRel[i][0] * k0 + sRel[i][1] * k1 + sRel[i][2] * k2;
      if (i == 0 && j == 0) v += 1.0f;
      v = fmaxf(v, 0.f);
      col[i] = v; s1 += v;
    }
    float inv1 = 1.0f / (s1 + 1e-6f);
    float s2 = 0.f;
#pragma unroll
    for (int i = 0; i < 32; ++i) { float v = col[i] * inv1; v = v * v; col[i] = v; s2 += v; }
    float inv2 = 1.0f / (s2 + 1e-6f);
#pragma unroll
    for (int i = 0; i < 32; ++i) {
      float v = col[i] * inv2;
      sP[i][j] = (v > 0.1f) ? v : 0.f;
    }
  }
  __syncthreads();

  // S5: feats @ P -> A[p][t*16 .. t*16+15] bf16
  {
    int c = t >> 1, h = (t & 1) * 16;
    float acc[16];
#pragma unroll
    for (int u = 0; u < 16; ++u) acc[u] = 0.f;
#pragma unroll 8
    for (int i = 0; i < 32; ++i) {
      float f = sFs[c][i];
#pragma unroll
      for (int u = 0; u < 16; ++u) acc[u] += f * sP[i][h + u];
    }
    unsigned pack[8];
#pragma unroll
    for (int u = 0; u < 8; ++u)
      pack[u] = (unsigned)f2bf(acc[2 * u]) | ((unsigned)f2bf(acc[2 * u + 1]) << 16);
    uint4* dst = (uint4*)(A + (size_t)p * 4096 + t * 16);
    dst[0] = make_uint4(pack[0], pack[1], pack[2], pack[3]);
    dst[1] = make_uint4(pack[4], pack[5], pack[6], pack[7]);
  }
}

// ---------------------------------------------------------------------------
// Phase 2: bf16 MFMA GEMM. C[m,n] = sum_k A[m,k]*W[n,k]. M=16384,N=128,K=4096.
// BM=64, BN=128, BK=32. 256 blocks, 4 waves, wave tile 32x64.
// Epilogue fuses bias + transpose to out[B,C,N].
// ---------------------------------------------------------------------------
__global__ __launch_bounds__(256) void paiconv_gemm(
    const void* __restrict__ xprobe,    // x, for dtype probe only
    const ushort_t* __restrict__ A,     // [16384,4096] bf16
    const void* __restrict__ W,         // [128,4096] conv_w
    const void* __restrict__ bias,      // [128] conv_b
    void* __restrict__ out)             // [8,128,2048]
{
  const bool bf = detect_bf16(xprobe);
  __shared__ ushort_t lA[64 * 32];
  __shared__ ushort_t lB[128 * 32];
  const int m0 = blockIdx.x * 64;
  const int t = threadIdx.x;
  const int w = t >> 6, lane = t & 63;
  const int wm = w & 1, wn = w >> 1;
  const int lrow = lane & 15, quad = lane >> 4;

  floatx4 acc[2][4];
#pragma unroll
  for (int i = 0; i < 2; ++i)
#pragma unroll
    for (int j = 0; j < 4; ++j) acc[i][j] = (floatx4){0.f, 0.f, 0.f, 0.f};

  const int arow = t >> 2;         // 0..63
  const int acol = (t & 3) * 8;    // 0,8,16,24 (bf16 elements)

  for (int kb = 0; kb < 128; ++kb) {
    const int k0 = kb * 32;
    uint4 va = *(const uint4*)(A + (size_t)(m0 + arow) * 4096 + k0 + acol);
    uint4 vb0, vb1;
    if (bf) {
      const ushort_t* Wu = (const ushort_t*)W;
      vb0 = *(const uint4*)(Wu + (size_t)arow * 4096 + k0 + acol);
      vb1 = *(const uint4*)(Wu + (size_t)(64 + arow) * 4096 + k0 + acol);
    } else {
      const float* Wf = (const float*)W;
      vb0 = pack8f(Wf + (size_t)arow * 4096 + k0 + acol);
      vb1 = pack8f(Wf + (size_t)(64 + arow) * 4096 + k0 + acol);
    }
    __syncthreads();   // previous iteration's ds_reads complete
    *(uint4*)(lA + arow * 32 + acol)        = va;
    *(uint4*)(lB + arow * 32 + acol)        = vb0;
    *(uint4*)(lB + (64 + arow) * 32 + acol) = vb1;
    __syncthreads();

    short8 af[2], bfr[4];
#pragma unroll
    for (int mi = 0; mi < 2; ++mi)
      af[mi] = *(const short8*)(lA + (wm * 32 + mi * 16 + lrow) * 32 + quad * 8);
#pragma unroll
    for (int ni = 0; ni < 4; ++ni)
      bfr[ni] = *(const short8*)(lB + (wn * 64 + ni * 16 + lrow) * 32 + quad * 8);
#pragma unroll
    for (int mi = 0; mi < 2; ++mi)
#pragma unroll
      for (int ni = 0; ni < 4; ++ni)
        acc[mi][ni] = __builtin_amdgcn_mfma_f32_16x16x32_bf16(
            af[mi], bfr[ni], acc[mi][ni], 0, 0, 0);
  }

  // epilogue: bias + transpose to [B, C_out, N]
  const int b   = m0 >> 11;
  const int npb = m0 & 2047;
#pragma unroll
  for (int mi = 0; mi < 2; ++mi)
#pragma unroll
    for (int ni = 0; ni < 4; ++ni) {
      int c = wn * 64 + ni * 16 + lrow;
      float bv = ldin(bias, c, bf);
      int np0 = npb + wm * 32 + mi * 16 + quad * 4;
      int oidx = b * 262144 + c * 2048 + np0;
      if (bf) {
        unsigned lo = (unsigned)f2bf(acc[mi][ni][0] + bv) |
                      ((unsigned)f2bf(acc[mi][ni][1] + bv) << 16);
        unsigned hi = (unsigned)f2bf(acc[mi][ni][2] + bv) |
                      ((unsigned)f2bf(acc[mi][ni][3] + bv) << 16);
        *(uint2*)((ushort_t*)out + oidx) = make_uint2(lo, hi);
      } else {
        *(float4*)((float*)out + oidx) = make_float4(
            acc[mi][ni][0] + bv, acc[mi][ni][1] + bv,
            acc[mi][ni][2] + bv, acc[mi][ni][3] + bv);
      }
    }
}

extern "C" void kernel_launch(void* const* d_in, const int* in_sizes, int n_in,
                              void* d_out, int out_size, void* d_ws, size_t ws_size,
                              hipStream_t stream) {
  const void* x     = d_in[0];
  const void* feat  = d_in[1];
  const int*  nbr   = (const int*)d_in[2];
  const void* Brff  = d_in[3];
  const void* kern  = d_in[4];
  const void* mlpw  = d_in[5];
  const void* mlpb  = d_in[6];
  const void* convw = d_in[7];
  const void* convb = d_in[8];

  ushort_t* A = (ushort_t*)d_ws;   // 16384*4096 bf16 = 128 MiB

  paiconv_phase1<<<16384, 256, 0, stream>>>(x, feat, nbr, Brff, kern, mlpw, mlpb, A);
  paiconv_gemm<<<256, 256, 0, stream>>>(x, A, convw, convb, d_out);
}

// Round 4
// 272.170 us; speedup vs baseline: 1.8557x; 1.8557x over previous
//
#include <hip/hip_runtime.h>

typedef unsigned short ushort_t;
typedef __attribute__((ext_vector_type(8))) short short8;
typedef __attribute__((ext_vector_type(4))) float floatx4;

#define TWO_PI 6.28318530717958647692f

__device__ __forceinline__ float bf2f(ushort_t u) {
  union { unsigned u; float f; } v; v.u = ((unsigned)u) << 16; return v.f;
}
__device__ __forceinline__ ushort_t f2bf(float f) {
  union { float f; unsigned u; } v; v.f = f;
  unsigned r = v.u + 0x7FFFu + ((v.u >> 16) & 1u);
  return (ushort_t)(r >> 16);
}
__device__ __forceinline__ unsigned pk(float a, float b) {
  return (unsigned)f2bf(a) | ((unsigned)f2bf(b) << 16);
}
__device__ __forceinline__ float ldin(const void* p, int idx, bool bf) {
  return bf ? bf2f(((const ushort_t*)p)[idx]) : ((const float*)p)[idx];
}
__device__ __forceinline__ bool detect_bf16(const void* xv) {
  const ushort_t* us = (const ushort_t*)xv;
  unsigned u = us[threadIdx.x & 63];
  int e = (u >> 7) & 0xFF;
  bool good = (e >= 110) && (e <= 133);
  unsigned long long m = __ballot(good);
  return __builtin_popcountll(m) >= 52;
}
__device__ __forceinline__ uint4 pack8f(const float* p) {
  float4 a = *(const float4*)p, b = *(const float4*)(p + 4);
  uint4 r;
  r.x = pk(a.x, a.y); r.y = pk(a.z, a.w);
  r.z = pk(b.x, b.y); r.w = pk(b.z, b.w);
  return r;
}

// ---------------------------------------------------------------------------
// Wconv: conv_w -> bf16 copy in ws (so GEMM always reads bf16 rows).
// ---------------------------------------------------------------------------
__global__ __launch_bounds__(256) void paiconv_wconv(
    const void* __restrict__ xprobe, const void* __restrict__ W,
    ushort_t* __restrict__ Wc)
{
  const bool bfm = detect_bf16(xprobe);
  int i = (blockIdx.x * 256 + threadIdx.x) << 3;   // 8 elems/thread
  if (bfm) *(uint4*)(Wc + i) = *(const uint4*)((const ushort_t*)W + i);
  else     *(uint4*)(Wc + i) = pack8f((const float*)W + i);
}

// ---------------------------------------------------------------------------
// Phase 1: 4 points/block, 256 threads. MFMA for mlp and feats@perm.
// Writes A[p][4096] bf16 (shuffled-channel-major: col = c2*32 + j).
// ---------------------------------------------------------------------------
__global__ __launch_bounds__(256) void paiconv_phase1(
    const void* __restrict__ x,      // [8,3,2048]
    const void* __restrict__ feat,   // [8,64,2048]
    const int*  __restrict__ nbr,    // [8,2048,32]
    const void* __restrict__ Brff,   // [7,32]
    const void* __restrict__ kern,   // [3,32]
    const void* __restrict__ mlpw,   // [64,64]
    const void* __restrict__ mlpb,   // [64]
    ushort_t*   __restrict__ Ag)     // [16384,4096] bf16
{
  const bool bfm = detect_bf16(x);
  const int t = threadIdx.x;
  const int p0 = blockIdx.x << 2;       // 4 points
  const int b  = p0 >> 11;
  const int w = t >> 6, lane = t & 63, lrow = lane & 15, quad = lane >> 4;

  // R^T[jn][q] bf16, stride 72 (rows 144B: 16B-aligned, 2-way banks)
  __shared__ ushort_t sRt[128 * 72];
  // F[pt][c2][i] bf16, stride 40 (rows 80B: aligned, even banks)
  __shared__ ushort_t sF[4 * 128 * 40];
  // union: mlpw bf16 [64][72] (<=4599) THEN P^T [pt][j][i] stride 40 (5120)
  __shared__ ushort_t sU[4 * 32 * 40];
  __shared__ float sRel[4][32][3];
  __shared__ float sDis[4][32];
  __shared__ float sRep[4][3];
  __shared__ int   sNb[4][32];
  __shared__ float sBr[224];
  __shared__ float sKn[96];
  __shared__ float sMb[64];

  // ---- step 0/1: constants to LDS, neighbor geometry ----
  if (t < 224) sBr[t] = ldin(Brff, t, bfm);
  if (t < 96)  sKn[t] = ldin(kern, t, bfm);
  if (t < 64)  sMb[t] = ldin(mlpb, t, bfm);
  {
    int c = t >> 2, q0 = (t & 3) << 4;   // 16 mlpw elems/thread
    unsigned wp[8];
#pragma unroll
    for (int qq = 0; qq < 16; qq += 2)
      wp[qq >> 1] = pk(ldin(mlpw, c * 64 + q0 + qq, bfm),
                       ldin(mlpw, c * 64 + q0 + qq + 1, bfm));
    *(uint4*)(sU + c * 72 + q0)     = make_uint4(wp[0], wp[1], wp[2], wp[3]);
    *(uint4*)(sU + c * 72 + q0 + 8) = make_uint4(wp[4], wp[5], wp[6], wp[7]);
  }
  if (t < 128) {
    int pt = t >> 5, i = t & 31;
    int p = p0 + pt;
    int idx  = nbr[(p << 5) + i];
    int idx0 = nbr[(p << 5)];
    sNb[pt][i] = idx;
    int xo = b * 6144;
    float rx = ldin(x, xo + idx0, bfm);
    float ry = ldin(x, xo + 2048 + idx0, bfm);
    float rz = ldin(x, xo + 4096 + idx0, bfm);
    float cx = ldin(x, xo + idx, bfm);
    float cy = ldin(x, xo + 2048 + idx, bfm);
    float cz = ldin(x, xo + 4096 + idx, bfm);
    float dx = cx - rx, dy = cy - ry, dz = cz - rz;
    sRel[pt][i][0] = dx; sRel[pt][i][1] = dy; sRel[pt][i][2] = dz;
    sDis[pt][i] = sqrtf(dx * dx + dy * dy + dz * dz);
    if (i == 0) { sRep[pt][0] = rx; sRep[pt][1] = ry; sRep[pt][2] = rz; }
  }
  __syncthreads();   // b1

  // ---- step 2: R^T build (sin|cos of RFF), bf16 ----
  {
    int jn = t >> 1, mh = (t & 1) << 4;   // 16 m's per thread
    int pt = jn >> 5, j = jn & 31;
    float pos[7];
    pos[0] = TWO_PI * sRep[pt][0]; pos[1] = TWO_PI * sRep[pt][1];
    pos[2] = TWO_PI * sRep[pt][2];
    pos[3] = TWO_PI * sRel[pt][j][0]; pos[4] = TWO_PI * sRel[pt][j][1];
    pos[5] = TWO_PI * sRel[pt][j][2];
    pos[6] = TWO_PI * sDis[pt][j];
    unsigned sw[8], cw[8];
#pragma unroll
    for (int mm = 0; mm < 16; mm += 2) {
      float a0 = 0.f, a1 = 0.f;
#pragma unroll
      for (int d = 0; d < 7; ++d) {
        a0 += pos[d] * sBr[d * 32 + mh + mm];
        a1 += pos[d] * sBr[d * 32 + mh + mm + 1];
      }
      sw[mm >> 1] = pk(__sinf(a0), __sinf(a1));
      cw[mm >> 1] = pk(__cosf(a0), __cosf(a1));
    }
    ushort_t* rb = sRt + jn * 72;
    *(uint4*)(rb + mh)          = make_uint4(sw[0], sw[1], sw[2], sw[3]);
    *(uint4*)(rb + mh + 8)      = make_uint4(sw[4], sw[5], sw[6], sw[7]);
    *(uint4*)(rb + 32 + mh)     = make_uint4(cw[0], cw[1], cw[2], cw[3]);
    *(uint4*)(rb + 32 + mh + 8) = make_uint4(cw[4], cw[5], cw[6], cw[7]);
  }
  __syncthreads();   // b2

  // ---- step 3: mlp MFMA: C[jn][c] = sum_q R^T[jn,q]*mlpw[c,q] + b[c] ----
  // writes F rows (c&31)*4 + 2 + (c>>5)  (rows == 2,3 mod 4)
  {
    int c = (w << 4) + lrow;
    int row = (c & 31) * 4 + 2 + (c >> 5);
    float bv = sMb[c];
    short8 b0 = *(const short8*)(sU + c * 72 + (quad << 3));
    short8 b1 = *(const short8*)(sU + c * 72 + 32 + (quad << 3));
#pragma unroll
    for (int mt = 0; mt < 8; ++mt) {
      const ushort_t* rp = sRt + (mt * 16 + lrow) * 72 + (quad << 3);
      short8 a0 = *(const short8*)rp;
      short8 a1 = *(const short8*)(rp + 32);
      floatx4 acc = {0.f, 0.f, 0.f, 0.f};
      acc = __builtin_amdgcn_mfma_f32_16x16x32_bf16(a0, b0, acc, 0, 0, 0);
      acc = __builtin_amdgcn_mfma_f32_16x16x32_bf16(a1, b1, acc, 0, 0, 0);
      int pt = mt >> 1;
      int j0 = ((mt & 1) << 4) + (quad << 2);
      *(uint2*)(sF + pt * 5120 + row * 40 + j0) =
          make_uint2(pk(acc[0] + bv, acc[1] + bv), pk(acc[2] + bv, acc[3] + bv));
    }
  }

  // ---- step 4: feature gather -> F rows 4*cc + ch (rows 0,1 mod 4) ----
  {
    int pt = t >> 6, j = (t >> 1) & 31, ch = t & 1;
    int idx = sNb[pt][j];
    ushort_t* dst = sF + pt * 5120 + ch * 40 + j;
    size_t base = ((size_t)(b * 64 + ch * 32) << 11) + idx;
    if (bfm) {
      const ushort_t* fb = (const ushort_t*)feat;
#pragma unroll
      for (int cc = 0; cc < 32; ++cc) dst[cc * 160] = fb[base + ((size_t)cc << 11)];
    } else {
      const float* fb = (const float*)feat;
#pragma unroll
      for (int cc = 0; cc < 32; ++cc) dst[cc * 160] = f2bf(fb[base + ((size_t)cc << 11)]);
    }
  }
  __syncthreads();   // b3

  // ---- step 5: perm build (fp32 math), store P^T bf16 into sU ----
  if (t < 128) {
    int pt = t >> 5, j = t & 31;
    float k0 = sKn[j], k1 = sKn[32 + j], k2 = sKn[64 + j];
    float col[32];
    float s1 = 0.f;
#pragma unroll
    for (int i = 0; i < 32; ++i) {
      float v = sRel[pt][i][0] * k0 + sRel[pt][i][1] * k1 + sRel[pt][i][2] * k2;
      if (i == 0 && j == 0) v += 1.0f;
      v = fmaxf(v, 0.f);
      col[i] = v; s1 += v;
    }
    float inv1 = 1.0f / (s1 + 1e-6f);
    float s2 = 0.f;
#pragma unroll
    for (int i = 0; i < 32; ++i) { float v = col[i] * inv1; v = v * v; col[i] = v; s2 += v; }
    float inv2 = 1.0f / (s2 + 1e-6f);
    unsigned pw[16];
#pragma unroll
    for (int i = 0; i < 32; i += 2) {
      float v0 = col[i] * inv2;     v0 = (v0 > 0.1f) ? v0 : 0.f;
      float v1 = col[i + 1] * inv2; v1 = (v1 > 0.1f) ? v1 : 0.f;
      pw[i >> 1] = pk(v0, v1);
    }
    ushort_t* dst = sU + pt * 1280 + j * 40;
#pragma unroll
    for (int g = 0; g < 4; ++g)
      *(uint4*)(dst + g * 8) = make_uint4(pw[4 * g], pw[4 * g + 1], pw[4 * g + 2], pw[4 * g + 3]);
  }
  __syncthreads();   // b4

  // ---- step 6: F@P via MFMA (A=P^T rows, B=F rows) -> global A ----
  {
#pragma unroll
    for (int pt = 0; pt < 4; ++pt) {
      const ushort_t* Pp = sU + pt * 1280;
      short8 a0 = *(const short8*)(Pp + lrow * 40 + (quad << 3));
      short8 a1 = *(const short8*)(Pp + (16 + lrow) * 40 + (quad << 3));
      size_t prow = ((size_t)(p0 + pt)) << 12;
#pragma unroll
      for (int nt = 0; nt < 2; ++nt) {
        int cidx = ((w * 2 + nt) << 4) + lrow;
        short8 bfg = *(const short8*)(sF + pt * 5120 + cidx * 40 + (quad << 3));
        floatx4 z = {0.f, 0.f, 0.f, 0.f};
        floatx4 c0 = __builtin_amdgcn_mfma_f32_16x16x32_bf16(a0, bfg, z, 0, 0, 0);
        floatx4 c1 = __builtin_amdgcn_mfma_f32_16x16x32_bf16(a1, bfg, z, 0, 0, 0);
        ushort_t* ad = Ag + prow + cidx * 32 + (quad << 2);
        *(uint2*)ad        = make_uint2(pk(c0[0], c0[1]), pk(c0[2], c0[3]));
        *(uint2*)(ad + 16) = make_uint2(pk(c1[0], c1[1]), pk(c1[2], c1[3]));
      }
    }
  }
}

// ---------------------------------------------------------------------------
// Phase 2: bf16 MFMA GEMM. C[m,n] = sum_k A[m,k]*Wc[n,k]. M=16384,N=128,K=4096.
// BM=32, BN=128, BK=64. 512 blocks (2/CU), register prefetch pipeline.
// Epilogue: bias + transpose to out[B,C,N].
// ---------------------------------------------------------------------------
__global__ __launch_bounds__(256) void paiconv_gemm(
    const void* __restrict__ xprobe,
    const ushort_t* __restrict__ A,     // [16384,4096] bf16
    const ushort_t* __restrict__ Wc,    // [128,4096] bf16
    const void* __restrict__ bias,      // [128]
    void* __restrict__ out)             // [8,128,2048]
{
  const bool bfm = detect_bf16(xprobe);
  __shared__ ushort_t lA[32 * 72];
  __shared__ ushort_t lB[128 * 72];
  const int m0 = blockIdx.x << 5;
  const int t = threadIdx.x;
  const int w = t >> 6, lane = t & 63, lrow = lane & 15, quad = lane >> 4;
  const int row = t >> 3, chunk = (t & 7) << 3;

  const ushort_t* Ap = A + (size_t)(m0 + row) * 4096 + chunk;
  const ushort_t* Wp = Wc + (size_t)row * 4096 + chunk;

  uint4 ra  = *(const uint4*)Ap;
  uint4 rb0 = *(const uint4*)Wp;
  uint4 rb1 = *(const uint4*)(Wp + 32 * 4096);
  uint4 rb2 = *(const uint4*)(Wp + 64 * 4096);
  uint4 rb3 = *(const uint4*)(Wp + 96 * 4096);

  floatx4 acc[2][2];
#pragma unroll
  for (int i = 0; i < 2; ++i)
#pragma unroll
    for (int j = 0; j < 2; ++j) acc[i][j] = (floatx4){0.f, 0.f, 0.f, 0.f};

  for (int kb = 0; kb < 64; ++kb) {
    __syncthreads();
    *(uint4*)(lA + row * 72 + chunk)        = ra;
    *(uint4*)(lB + row * 72 + chunk)        = rb0;
    *(uint4*)(lB + (32 + row) * 72 + chunk) = rb1;
    *(uint4*)(lB + (64 + row) * 72 + chunk) = rb2;
    *(uint4*)(lB + (96 + row) * 72 + chunk) = rb3;
    __syncthreads();
    if (kb < 63) {
      int off = (kb + 1) * 64;
      ra  = *(const uint4*)(Ap + off);
      rb0 = *(const uint4*)(Wp + off);
      rb1 = *(const uint4*)(Wp + 32 * 4096 + off);
      rb2 = *(const uint4*)(Wp + 64 * 4096 + off);
      rb3 = *(const uint4*)(Wp + 96 * 4096 + off);
    }
#pragma unroll
    for (int kk = 0; kk < 2; ++kk) {
      short8 a0 = *(const short8*)(lA + lrow * 72 + kk * 32 + (quad << 3));
      short8 a1 = *(const short8*)(lA + (16 + lrow) * 72 + kk * 32 + (quad << 3));
#pragma unroll
      for (int ni = 0; ni < 2; ++ni) {
        short8 bfg = *(const short8*)(lB + ((w << 5) + (ni << 4) + lrow) * 72 +
                                      kk * 32 + (quad << 3));
        acc[0][ni] = __builtin_amdgcn_mfma_f32_16x16x32_bf16(a0, bfg, acc[0][ni], 0, 0, 0);
        acc[1][ni] = __builtin_amdgcn_mfma_f32_16x16x32_bf16(a1, bfg, acc[1][ni], 0, 0, 0);
      }
    }
  }

  const int b = m0 >> 11;
  const int npb = (m0 & 2047) + (quad << 2);
#pragma unroll
  for (int mi = 0; mi < 2; ++mi)
#pragma unroll
    for (int ni = 0; ni < 2; ++ni) {
      int c = (w << 5) + (ni << 4) + lrow;
      float bv = ldin(bias, c, bfm);
      int np = npb + (mi << 4);
      size_t o = (size_t)b * 262144 + (size_t)c * 2048 + np;
      if (bfm) {
        *(uint2*)((ushort_t*)out + o) =
            make_uint2(pk(acc[mi][ni][0] + bv, acc[mi][ni][1] + bv),
                       pk(acc[mi][ni][2] + bv, acc[mi][ni][3] + bv));
      } else {
        *(float4*)((float*)out + o) =
            make_float4(acc[mi][ni][0] + bv, acc[mi][ni][1] + bv,
                        acc[mi][ni][2] + bv, acc[mi][ni][3] + bv);
      }
    }
}

extern "C" void kernel_launch(void* const* d_in, const int* in_sizes, int n_in,
                              void* d_out, int out_size, void* d_ws, size_t ws_size,
                              hipStream_t stream) {
  const void* x     = d_in[0];
  const void* feat  = d_in[1];
  const int*  nbr   = (const int*)d_in[2];
  const void* Brff  = d_in[3];
  const void* kern  = d_in[4];
  const void* mlpw  = d_in[5];
  const void* mlpb  = d_in[6];
  const void* convw = d_in[7];
  const void* convb = d_in[8];

  ushort_t* A  = (ushort_t*)d_ws;                                   // 128 MiB
  ushort_t* Wc = (ushort_t*)((char*)d_ws + (size_t)16384 * 4096 * 2); // +1 MiB

  paiconv_wconv<<<256, 256, 0, stream>>>(x, convw, Wc);
  paiconv_phase1<<<4096, 256, 0, stream>>>(x, feat, nbr, Brff, kern, mlpw, mlpb, A);
  paiconv_gemm<<<512, 256, 0, stream>>>(x, A, Wc, convb, d_out);
}

// Round 5
// 198.488 us; speedup vs baseline: 2.5445x; 1.3712x over previous
//
#include <hip/hip_runtime.h>

typedef unsigned short ushort_t;
typedef __attribute__((ext_vector_type(8))) short short8;
typedef __attribute__((ext_vector_type(4))) float floatx4;

#define TWO_PI 6.28318530717958647692f

__device__ __forceinline__ float bf2f(ushort_t u) {
  union { unsigned u; float f; } v; v.u = ((unsigned)u) << 16; return v.f;
}
__device__ __forceinline__ ushort_t f2bf(float f) {
  union { float f; unsigned u; } v; v.f = f;
  unsigned r = v.u + 0x7FFFu + ((v.u >> 16) & 1u);
  return (ushort_t)(r >> 16);
}
__device__ __forceinline__ unsigned pk(float a, float b) {
  return (unsigned)f2bf(a) | ((unsigned)f2bf(b) << 16);
}
__device__ __forceinline__ float ldin(const void* p, int idx, bool bf) {
  return bf ? bf2f(((const ushort_t*)p)[idx]) : ((const float*)p)[idx];
}
__device__ __forceinline__ bool detect_bf16(const void* xv) {
  const ushort_t* us = (const ushort_t*)xv;
  unsigned u = us[threadIdx.x & 63];
  int e = (u >> 7) & 0xFF;
  bool good = (e >= 110) && (e <= 133);
  unsigned long long m = __ballot(good);
  return __builtin_popcountll(m) >= 52;
}
__device__ __forceinline__ uint4 pack8f(const float* p) {
  float4 a = *(const float4*)p, b = *(const float4*)(p + 4);
  uint4 r;
  r.x = pk(a.x, a.y); r.y = pk(a.z, a.w);
  r.z = pk(b.x, b.y); r.w = pk(b.z, b.w);
  return r;
}

// ---------------------------------------------------------------------------
// Wconv: conv_w -> bf16 copy in ws.
// ---------------------------------------------------------------------------
__global__ __launch_bounds__(256) void paiconv_wconv(
    const void* __restrict__ xprobe, const void* __restrict__ W,
    ushort_t* __restrict__ Wc)
{
  const bool bfm = detect_bf16(xprobe);
  int i = (blockIdx.x * 256 + threadIdx.x) << 3;
  if (bfm) *(uint4*)(Wc + i) = *(const uint4*)((const ushort_t*)W + i);
  else     *(uint4*)(Wc + i) = pack8f((const float*)W + i);
}

// ---------------------------------------------------------------------------
// featT: feat[8][64][2048] -> Ft[b*2048+n][64] bf16 (128B contiguous rows).
// Grid 256: blockIdx = b*32 + ntile. Tile 64n x 64c via LDS.
// ---------------------------------------------------------------------------
__global__ __launch_bounds__(256) void paiconv_featT(
    const void* __restrict__ xprobe, const void* __restrict__ feat,
    ushort_t* __restrict__ Ft)
{
  const bool bfm = detect_bf16(xprobe);
  const int t = threadIdx.x;
  const int bb = blockIdx.x >> 5;
  const int n0 = (blockIdx.x & 31) << 6;
  __shared__ ushort_t tile[64 * 72];   // [n'][c], stride 72 (144B, 16B-aligned)
  {
    const int c = t & 63, ng = t >> 6;   // wave w handles n' = w*16..+16
    size_t base = (((size_t)(bb * 64 + c)) << 11) + n0 + (ng << 4);
    ushort_t v[16];
    if (bfm) {
      const ushort_t* fp_ = (const ushort_t*)feat + base;
      uint4 a = *(const uint4*)fp_, b2 = *(const uint4*)(fp_ + 8);
      unsigned uu[8] = {a.x, a.y, a.z, a.w, b2.x, b2.y, b2.z, b2.w};
#pragma unroll
      for (int e = 0; e < 8; ++e) {
        v[2 * e] = (ushort_t)(uu[e] & 0xffff);
        v[2 * e + 1] = (ushort_t)(uu[e] >> 16);
      }
    } else {
      const float* fp_ = (const float*)feat + base;
#pragma unroll
      for (int k = 0; k < 16; ++k) v[k] = f2bf(fp_[k]);
    }
#pragma unroll
    for (int k = 0; k < 16; ++k) tile[(ng * 16 + k) * 72 + c] = v[k];
  }
  __syncthreads();
  {
    const int nn = t >> 2, qtr = t & 3;
    uint4 w0 = *(const uint4*)(tile + nn * 72 + qtr * 16);
    uint4 w1 = *(const uint4*)(tile + nn * 72 + qtr * 16 + 8);
    ushort_t* dst = Ft + (((size_t)(bb * 2048 + n0 + nn)) << 6) + (qtr << 4);
    *(uint4*)dst = w0;
    *(uint4*)(dst + 8) = w1;
  }
}

// ---------------------------------------------------------------------------
// Phase 1: 4 points/block. Gather prefetched to registers at entry (from Ft).
// MFMA for mlp and feats@perm. Writes A[p][4096] bf16.
// ---------------------------------------------------------------------------
__global__ __launch_bounds__(256) void paiconv_phase1(
    const void* __restrict__ x,       // [8,3,2048]
    const ushort_t* __restrict__ Ft,  // [16384][64] bf16
    const int*  __restrict__ nbr,     // [8,2048,32]
    const void* __restrict__ Brff,    // [7,32]
    const void* __restrict__ kern,    // [3,32]
    const void* __restrict__ mlpw,    // [64,64]
    const void* __restrict__ mlpb,    // [64]
    ushort_t*   __restrict__ Ag)      // [16384,4096] bf16
{
  const bool bfm = detect_bf16(x);
  const int t = threadIdx.x;
  const int p0 = blockIdx.x << 2;
  const int b  = p0 >> 11;
  const int w = t >> 6, lane = t & 63, lrow = lane & 15, quad = lane >> 4;

  __shared__ ushort_t sRt[128 * 72];  // R^T[jn][q] stride 72
  __shared__ ushort_t sF[4 * 128 * 40]; // F[pt][c'][i] stride 40
  __shared__ ushort_t sU[4 * 32 * 40];  // mlpw[64][72] then P^T[pt][j][i]
  __shared__ float sRel[4][32][3];
  __shared__ float sDis[4][32];
  __shared__ float sRep[4][3];
  __shared__ float sBr[224];
  __shared__ float sKn[96];
  __shared__ float sMb[64];

  // ---- gather prefetch: 32 channels (4 uint4) per thread, issued first ----
  const int gpt = w, gj = (t >> 1) & 31, gh = t & 1;
  const int gidx = nbr[((p0 + gpt) << 5) + gj];
  const ushort_t* gfr = Ft + (((size_t)(b * 2048 + gidx)) << 6) + (gh << 5);
  uint4 g0 = ((const uint4*)gfr)[0];
  uint4 g1 = ((const uint4*)gfr)[1];
  uint4 g2 = ((const uint4*)gfr)[2];
  uint4 g3 = ((const uint4*)gfr)[3];

  // ---- constants to LDS ----
  if (t < 224) sBr[t] = ldin(Brff, t, bfm);
  if (t < 96)  sKn[t] = ldin(kern, t, bfm);
  if (t < 64)  sMb[t] = ldin(mlpb, t, bfm);
  {
    int c = t >> 2, q0 = (t & 3) << 4;
    uint4 w0, w1;
    if (bfm) {
      const ushort_t* mp = (const ushort_t*)mlpw + c * 64 + q0;
      w0 = *(const uint4*)mp; w1 = *(const uint4*)(mp + 8);
    } else {
      const float* mp = (const float*)mlpw + c * 64 + q0;
      w0 = pack8f(mp); w1 = pack8f(mp + 8);
    }
    *(uint4*)(sU + c * 72 + q0) = w0;
    *(uint4*)(sU + c * 72 + q0 + 8) = w1;
  }
  // ---- neighbor geometry ----
  if (t < 128) {
    int pt = t >> 5, i = t & 31;
    int p = p0 + pt;
    int idx  = nbr[(p << 5) + i];
    int idx0 = nbr[(p << 5)];
    int xo = b * 6144;
    float rx = ldin(x, xo + idx0, bfm);
    float ry = ldin(x, xo + 2048 + idx0, bfm);
    float rz = ldin(x, xo + 4096 + idx0, bfm);
    float cx = ldin(x, xo + idx, bfm);
    float cy = ldin(x, xo + 2048 + idx, bfm);
    float cz = ldin(x, xo + 4096 + idx, bfm);
    float dx = cx - rx, dy = cy - ry, dz = cz - rz;
    sRel[pt][i][0] = dx; sRel[pt][i][1] = dy; sRel[pt][i][2] = dz;
    sDis[pt][i] = sqrtf(dx * dx + dy * dy + dz * dz);
    if (i == 0) { sRep[pt][0] = rx; sRep[pt][1] = ry; sRep[pt][2] = rz; }
  }
  __syncthreads();   // b1

  // ---- step 2: R^T build ----
  {
    int jn = t >> 1, mh = (t & 1) << 4;
    int pt = jn >> 5, j = jn & 31;
    float pos[7];
    pos[0] = TWO_PI * sRep[pt][0]; pos[1] = TWO_PI * sRep[pt][1];
    pos[2] = TWO_PI * sRep[pt][2];
    pos[3] = TWO_PI * sRel[pt][j][0]; pos[4] = TWO_PI * sRel[pt][j][1];
    pos[5] = TWO_PI * sRel[pt][j][2];
    pos[6] = TWO_PI * sDis[pt][j];
    unsigned sw[8], cw[8];
#pragma unroll
    for (int mm = 0; mm < 16; mm += 2) {
      float a0 = 0.f, a1 = 0.f;
#pragma unroll
      for (int d = 0; d < 7; ++d) {
        a0 += pos[d] * sBr[d * 32 + mh + mm];
        a1 += pos[d] * sBr[d * 32 + mh + mm + 1];
      }
      sw[mm >> 1] = pk(__sinf(a0), __sinf(a1));
      cw[mm >> 1] = pk(__cosf(a0), __cosf(a1));
    }
    ushort_t* rb = sRt + jn * 72;
    *(uint4*)(rb + mh)          = make_uint4(sw[0], sw[1], sw[2], sw[3]);
    *(uint4*)(rb + mh + 8)      = make_uint4(sw[4], sw[5], sw[6], sw[7]);
    *(uint4*)(rb + 32 + mh)     = make_uint4(cw[0], cw[1], cw[2], cw[3]);
    *(uint4*)(rb + 32 + mh + 8) = make_uint4(cw[4], cw[5], cw[6], cw[7]);
  }
  __syncthreads();   // b2

  // ---- step 3: mlp MFMA -> sF rows 2,3 mod 4 ----
  {
    int c = (w << 4) + lrow;
    int row = (c & 31) * 4 + 2 + (c >> 5);
    float bv = sMb[c];
    short8 b0 = *(const short8*)(sU + c * 72 + (quad << 3));
    short8 b1 = *(const short8*)(sU + c * 72 + 32 + (quad << 3));
#pragma unroll
    for (int mt = 0; mt < 8; ++mt) {
      const ushort_t* rp = sRt + (mt * 16 + lrow) * 72 + (quad << 3);
      short8 a0 = *(const short8*)rp;
      short8 a1 = *(const short8*)(rp + 32);
      floatx4 acc = {0.f, 0.f, 0.f, 0.f};
      acc = __builtin_amdgcn_mfma_f32_16x16x32_bf16(a0, b0, acc, 0, 0, 0);
      acc = __builtin_amdgcn_mfma_f32_16x16x32_bf16(a1, b1, acc, 0, 0, 0);
      int pt = mt >> 1;
      int j0 = ((mt & 1) << 4) + (quad << 2);
      *(uint2*)(sF + pt * 5120 + row * 40 + j0) =
          make_uint2(pk(acc[0] + bv, acc[1] + bv), pk(acc[2] + bv, acc[3] + bv));
    }
  }
  // ---- step 4: gather regs -> sF rows 0,1 mod 4 ----
  {
    ushort_t* fp_ = sF + gpt * 5120 + gh * 40 + gj;
    unsigned uu[16] = {g0.x, g0.y, g0.z, g0.w, g1.x, g1.y, g1.z, g1.w,
                       g2.x, g2.y, g2.z, g2.w, g3.x, g3.y, g3.z, g3.w};
#pragma unroll
    for (int e = 0; e < 16; ++e) {
      int cc = e * 2;                     // channel pair within half
      fp_[cc * 160]       = (ushort_t)(uu[e] & 0xffff);
      fp_[cc * 160 + 160] = (ushort_t)(uu[e] >> 16);
    }
  }
  __syncthreads();   // b3

  // ---- step 5: perm build -> P^T in sU ----
  if (t < 128) {
    int pt = t >> 5, j = t & 31;
    float k0 = sKn[j], k1 = sKn[32 + j], k2 = sKn[64 + j];
    float col[32];
    float s1 = 0.f;
#pragma unroll
    for (int i = 0; i < 32; ++i) {
      float v = sRel[pt][i][0] * k0 + sRel[pt][i][1] * k1 + sRel[pt][i][2] * k2;
      if (i == 0 && j == 0) v += 1.0f;
      v = fmaxf(v, 0.f);
      col[i] = v; s1 += v;
    }
    float inv1 = 1.0f / (s1 + 1e-6f);
    float s2 = 0.f;
#pragma unroll
    for (int i = 0; i < 32; ++i) { float v = col[i] * inv1; v = v * v; col[i] = v; s2 += v; }
    float inv2 = 1.0f / (s2 + 1e-6f);
    unsigned pw[16];
#pragma unroll
    for (int i = 0; i < 32; i += 2) {
      float v0 = col[i] * inv2;     v0 = (v0 > 0.1f) ? v0 : 0.f;
      float v1 = col[i + 1] * inv2; v1 = (v1 > 0.1f) ? v1 : 0.f;
      pw[i >> 1] = pk(v0, v1);
    }
    ushort_t* dst = sU + pt * 1280 + j * 40;
#pragma unroll
    for (int g = 0; g < 4; ++g)
      *(uint4*)(dst + g * 8) = make_uint4(pw[4 * g], pw[4 * g + 1], pw[4 * g + 2], pw[4 * g + 3]);
  }
  __syncthreads();   // b4

  // ---- step 6: F@P via MFMA -> global A ----
  {
#pragma unroll
    for (int pt = 0; pt < 4; ++pt) {
      const ushort_t* Pp = sU + pt * 1280;
      short8 a0 = *(const short8*)(Pp + lrow * 40 + (quad << 3));
      short8 a1 = *(const short8*)(Pp + (16 + lrow) * 40 + (quad << 3));
      size_t prow = ((size_t)(p0 + pt)) << 12;
#pragma unroll
      for (int nt = 0; nt < 2; ++nt) {
        int cidx = ((w * 2 + nt) << 4) + lrow;
        short8 bfg = *(const short8*)(sF + pt * 5120 + cidx * 40 + (quad << 3));
        floatx4 z = {0.f, 0.f, 0.f, 0.f};
        floatx4 c0 = __builtin_amdgcn_mfma_f32_16x16x32_bf16(a0, bfg, z, 0, 0, 0);
        floatx4 c1 = __builtin_amdgcn_mfma_f32_16x16x32_bf16(a1, bfg, z, 0, 0, 0);
        ushort_t* ad = Ag + prow + cidx * 32 + (quad << 2);
        *(uint2*)ad        = make_uint2(pk(c0[0], c0[1]), pk(c0[2], c0[3]));
        *(uint2*)(ad + 16) = make_uint2(pk(c1[0], c1[1]), pk(c1[2], c1[3]));
      }
    }
  }
}

// ---------------------------------------------------------------------------
// Phase 2: bf16 MFMA GEMM, BM=64, BN=128, BK=64, split-K=2 -> fp32 partials.
// Grid (256, 2): 2 blocks/CU. Register-prefetch pipeline.
// ---------------------------------------------------------------------------
__global__ __launch_bounds__(256) void paiconv_gemm(
    const ushort_t* __restrict__ A,    // [16384,4096] bf16
    const ushort_t* __restrict__ Wc,   // [128,4096] bf16
    float* __restrict__ part)          // [2][16384][128] fp32
{
  __shared__ ushort_t lA[64 * 72];
  __shared__ ushort_t lB[128 * 72];
  const int m0 = blockIdx.x << 6;
  const int K0 = blockIdx.y << 11;
  const int t = threadIdx.x;
  const int w = t >> 6, lane = t & 63, lrow = lane & 15, quad = lane >> 4;

  const int ar = t >> 2, ac = (t & 3) << 4;   // A: 64 rows x 64, 16 elems/thread
  const int wr = t >> 1, wc = (t & 1) << 5;   // W: 128 rows x 64, 32 elems/thread
  const ushort_t* Ap = A + (size_t)(m0 + ar) * 4096 + K0 + ac;
  const ushort_t* Wp = Wc + (size_t)wr * 4096 + K0 + wc;

  uint4 ra0 = *(const uint4*)Ap, ra1 = *(const uint4*)(Ap + 8);
  uint4 rb0 = *(const uint4*)Wp, rb1 = *(const uint4*)(Wp + 8);
  uint4 rb2 = *(const uint4*)(Wp + 16), rb3 = *(const uint4*)(Wp + 24);

  floatx4 acc[4][2];
#pragma unroll
  for (int i = 0; i < 4; ++i)
#pragma unroll
    for (int j = 0; j < 2; ++j) acc[i][j] = (floatx4){0.f, 0.f, 0.f, 0.f};

  for (int kb = 0; kb < 32; ++kb) {
    __syncthreads();
    *(uint4*)(lA + ar * 72 + ac)      = ra0;
    *(uint4*)(lA + ar * 72 + ac + 8)  = ra1;
    *(uint4*)(lB + wr * 72 + wc)      = rb0;
    *(uint4*)(lB + wr * 72 + wc + 8)  = rb1;
    *(uint4*)(lB + wr * 72 + wc + 16) = rb2;
    *(uint4*)(lB + wr * 72 + wc + 24) = rb3;
    __syncthreads();
    if (kb < 31) {
      int off = (kb + 1) << 6;
      ra0 = *(const uint4*)(Ap + off);      ra1 = *(const uint4*)(Ap + off + 8);
      rb0 = *(const uint4*)(Wp + off);      rb1 = *(const uint4*)(Wp + off + 8);
      rb2 = *(const uint4*)(Wp + off + 16); rb3 = *(const uint4*)(Wp + off + 24);
    }
#pragma unroll
    for (int kk = 0; kk < 2; ++kk) {
      short8 bf0 = *(const short8*)(lB + ((w << 5) + lrow) * 72 + kk * 32 + (quad << 3));
      short8 bf1 = *(const short8*)(lB + ((w << 5) + 16 + lrow) * 72 + kk * 32 + (quad << 3));
#pragma unroll
      for (int mi = 0; mi < 4; ++mi) {
        short8 af = *(const short8*)(lA + (mi * 16 + lrow) * 72 + kk * 32 + (quad << 3));
        acc[mi][0] = __builtin_amdgcn_mfma_f32_16x16x32_bf16(af, bf0, acc[mi][0], 0, 0, 0);
        acc[mi][1] = __builtin_amdgcn_mfma_f32_16x16x32_bf16(af, bf1, acc[mi][1], 0, 0, 0);
      }
    }
  }

  float* dst = part + ((size_t)blockIdx.y << 21);
#pragma unroll
  for (int mi = 0; mi < 4; ++mi)
#pragma unroll
    for (int ni = 0; ni < 2; ++ni)
#pragma unroll
      for (int r = 0; r < 4; ++r) {
        int m = m0 + mi * 16 + (quad << 2) + r;
        int n = (w << 5) + ni * 16 + lrow;
        dst[(size_t)m * 128 + n] = acc[mi][ni][r];
      }
}

// ---------------------------------------------------------------------------
// Reduce: sum 2 split-K partials + bias, transpose to out[B,C,N].
// ---------------------------------------------------------------------------
__global__ __launch_bounds__(256) void paiconv_reduce(
    const void* __restrict__ xprobe, const float* __restrict__ part,
    const void* __restrict__ bias, void* __restrict__ out)
{
  const bool bfm = detect_bf16(xprobe);
  __shared__ float buf[128 * 65];
  const int m0 = blockIdx.x << 6;
  const int b = m0 >> 11, n0 = m0 & 2047;
  const int t = threadIdx.x;

#pragma unroll 4
  for (int i = 0; i < 32; ++i) {
    int idx = i * 256 + t;
    int mt = idx >> 7, c = idx & 127;
    size_t o = (size_t)(m0 + mt) * 128 + c;
    float s = ldin(bias, c, bfm) + part[o] + part[(1u << 21) + o];
    buf[c * 65 + mt] = s;
  }
  __syncthreads();
#pragma unroll 4
  for (int i = 0; i < 32; ++i) {
    int idx = i * 256 + t;
    int c = idx >> 6, nl = idx & 63;
    float v = buf[c * 65 + nl];
    size_t o = (size_t)b * 262144 + (size_t)c * 2048 + n0 + nl;
    if (bfm) ((ushort_t*)out)[o] = f2bf(v);
    else     ((float*)out)[o] = v;
  }
}

extern "C" void kernel_launch(void* const* d_in, const int* in_sizes, int n_in,
                              void* d_out, int out_size, void* d_ws, size_t ws_size,
                              hipStream_t stream) {
  const void* x     = d_in[0];
  const void* feat  = d_in[1];
  const int*  nbr   = (const int*)d_in[2];
  const void* Brff  = d_in[3];
  const void* kern  = d_in[4];
  const void* mlpw  = d_in[5];
  const void* mlpb  = d_in[6];
  const void* convw = d_in[7];
  const void* convb = d_in[8];

  char* ws = (char*)d_ws;
  ushort_t* A   = (ushort_t*)ws;                          // 128 MiB
  ushort_t* Wcv = (ushort_t*)(ws + (size_t)134217728);    // 1 MiB
  float*    prt = (float*)(ws + (size_t)135266304);       // 16 MiB
  ushort_t* Ft  = (ushort_t*)(ws + (size_t)152043520);    // 2 MiB

  paiconv_wconv<<<256, 256, 0, stream>>>(x, convw, Wcv);
  paiconv_featT<<<256, 256, 0, stream>>>(x, feat, Ft);
  paiconv_phase1<<<4096, 256, 0, stream>>>(x, Ft, nbr, Brff, kern, mlpw, mlpb, A);
  paiconv_gemm<<<dim3(256, 2, 1), 256, 0, stream>>>(A, Wcv, prt);
  paiconv_reduce<<<256, 256, 0, stream>>>(x, prt, convb, d_out);
}